// Round 5
// baseline (115.963 us; speedup 1.0000x reference)
//
#include <hip/hip_runtime.h>
#include <stdint.h>

// SelfAttentionBlock: B=4, C=256, H=W=64 (N=4096), CQK=32.
//   cvt : W fp32->f16 (Wh) + x -> f16 transposed xh[b][n][c]   (fused kernel)
//   proj: register MFMA GEMM -> Qt[n][32]*log2e, Kt[n][32], V[c][n] (f16)
//   attn: flash attention, 8 waves = 2 j-split groups with PHASE-SKEW:
//         groups alternate QK/softmax vs PV roles between barriers so MFMA and
//         VALU phases overlap on every SIMD. Swapped QK^T (lane owns a row),
//         K global->reg (no LDS), counted vmcnt(12) staging, defer-max,
//         log2-domain softmax, conflict-free swizzled P/V LDS.

#define NB 4
#define CD 256
#define ND 4096
#define CQ 32
#define LOG2E 1.4426950408889634f

typedef __attribute__((ext_vector_type(4))) float f32x4;
typedef __attribute__((ext_vector_type(8))) _Float16 f16x8;
typedef __attribute__((ext_vector_type(2))) __fp16 h16x2;
typedef __attribute__((ext_vector_type(4))) unsigned short u16x4;
typedef __attribute__((ext_vector_type(8))) unsigned short u16x8;
typedef __attribute__((ext_vector_type(2))) unsigned int u32x2;

static __device__ __forceinline__ unsigned short f2h(float f) {
    union { _Float16 h; unsigned short u; } cv; cv.h = (_Float16)f; return cv.u;
}
static __device__ __forceinline__ float fexp2(float xv) {
    float r; asm("v_exp_f32 %0, %1" : "=v"(r) : "v"(xv)); return r;
}
__device__ __forceinline__ void gl_lds16(const void* gp, void* l) {
    __builtin_amdgcn_global_load_lds(
        (const __attribute__((address_space(1))) unsigned int*)gp,
        (__attribute__((address_space(3))) unsigned int*)l, 16, 0, 0);
}

#define BARRIER() asm volatile("s_waitcnt lgkmcnt(0)\n\ts_barrier" ::: "memory")

// ---------------- fused cvt: W fp32->f16 and x -> xh[b][n][c] f16 ----------------
// blocks 0..1023: xcvt; blocks 1024..1103: wcvt. 256 threads each.
__global__ __launch_bounds__(256) void cvt_kernel(
    const float* __restrict__ x,
    const float* __restrict__ wq, const float* __restrict__ wk,
    const float* __restrict__ wv,
    unsigned short* __restrict__ xh, unsigned short* __restrict__ Wh)
{
    __shared__ unsigned short xt[64 * 72];
    if (blockIdx.x >= 1024) {   // ---- wcvt part (80 blocks) ----
        const int idx = (blockIdx.x - 1024) * 256 + threadIdx.x;
        const int m = idx >> 6, kq = (idx & 63) << 2;
        const float* src = (m < 32) ? (wq + (size_t)m * CD + kq)
                         : (m < 64) ? (wk + (size_t)(m - 32) * CD + kq)
                                    : (wv + (size_t)(m - 64) * CD + kq);
        const f32x4 v = *reinterpret_cast<const f32x4*>(src);
        u16x4 h;
#pragma unroll
        for (int u = 0; u < 4; ++u) h[u] = f2h(v[u]);
        *reinterpret_cast<u16x4*>(Wh + (size_t)m * CD + kq) = h;
        return;
    }
    // ---- xcvt part (1024 blocks): 64x64 LDS transpose ----
    const int t  = threadIdx.x;
    const int nt = blockIdx.x & 63, ct = (blockIdx.x >> 6) & 3, b = blockIdx.x >> 8;
    const int n0 = nt << 6, c0 = ct << 6;

    const float* xb = x + ((size_t)(b * CD + c0)) * ND + n0;
#pragma unroll
    for (int s = t; s < 1024; s += 256) {
        const int c = s >> 4, nq = (s & 15) << 2;
        const f32x4 v = *reinterpret_cast<const f32x4*>(xb + (size_t)c * ND + nq);
        u16x4 h;
#pragma unroll
        for (int u = 0; u < 4; ++u) h[u] = f2h(v[u]);
        *reinterpret_cast<u16x4*>(&xt[c * 72 + nq]) = h;
    }
    __syncthreads();

    const int n = t >> 2, cb = (t & 3) << 4;
    u16x8 o0, o1;
#pragma unroll
    for (int u = 0; u < 8; ++u) o0[u] = xt[(cb + u) * 72 + n];
#pragma unroll
    for (int u = 0; u < 8; ++u) o1[u] = xt[(cb + 8 + u) * 72 + n];
    unsigned short* dst = xh + ((size_t)(b * ND + n0 + n)) * CD + c0 + cb;
    *reinterpret_cast<u16x8*>(dst)     = o0;
    *reinterpret_cast<u16x8*>(dst + 8) = o1;
}

// ---------------- projection: register MFMA GEMM ----------------
__global__ __launch_bounds__(320) void proj_kernel(
    const unsigned short* __restrict__ Wh, const unsigned short* __restrict__ xh,
    const float* __restrict__ bq, const float* __restrict__ bk,
    const float* __restrict__ bv,
    unsigned short* __restrict__ Qt, unsigned short* __restrict__ Kt,
    unsigned short* __restrict__ V)
{
    const int tid = threadIdx.x;
    const int lane = tid & 63;
    const int w = __builtin_amdgcn_readfirstlane(tid >> 6);
    const int m16 = lane & 15, g4 = lane >> 4;
    const int b = blockIdx.x >> 6, n0 = (blockIdx.x & 63) << 6;

    f32x4 acc[4][4];
#pragma unroll
    for (int a = 0; a < 4; ++a)
#pragma unroll
        for (int c = 0; c < 4; ++c) acc[a][c] = (f32x4){0.f, 0.f, 0.f, 0.f};

    const unsigned short* Wrow = Wh + (size_t)(w * 64 + m16) * CD;
    const unsigned short* Xrow = xh + ((size_t)(b * ND + n0 + m16)) * CD;

#pragma unroll
    for (int ks = 0; ks < 8; ++ks) {
        const int ko = ks * 32 + g4 * 8;
        f16x8 af[4], bf[4];
#pragma unroll
        for (int ms = 0; ms < 4; ++ms)
            af[ms] = *reinterpret_cast<const f16x8*>(Wrow + (size_t)ms * 16 * CD + ko);
#pragma unroll
        for (int ns = 0; ns < 4; ++ns)
            bf[ns] = *reinterpret_cast<const f16x8*>(Xrow + (size_t)ns * 16 * CD + ko);
#pragma unroll
        for (int ms = 0; ms < 4; ++ms)
#pragma unroll
            for (int ns = 0; ns < 4; ++ns)
                acc[ms][ns] = __builtin_amdgcn_mfma_f32_16x16x32_f16(
                    af[ms], bf[ns], acc[ms][ns], 0, 0, 0);
    }

#pragma unroll
    for (int ms = 0; ms < 4; ++ms) {
        const int seg = w * 64 + ms * 16;
        const int mb  = seg + g4 * 4;
        f32x4 bias;
        if (seg < 32)       bias = *reinterpret_cast<const f32x4*>(bq + mb);
        else if (seg < 64)  bias = *reinterpret_cast<const f32x4*>(bk + mb - 32);
        else                bias = *reinterpret_cast<const f32x4*>(bv + mb - 64);
#pragma unroll
        for (int ns = 0; ns < 4; ++ns) {
            const int n = n0 + ns * 16 + m16;
            u16x4 h;
            if (seg < 32) {
#pragma unroll
                for (int r = 0; r < 4; ++r)
                    h[r] = f2h(fmaxf(acc[ms][ns][r] + bias[r], 0.f) * LOG2E);
                *reinterpret_cast<u16x4*>(Qt + ((size_t)(b * ND + n)) * CQ + mb) = h;
            } else if (seg < 64) {
#pragma unroll
                for (int r = 0; r < 4; ++r) h[r] = f2h(fmaxf(acc[ms][ns][r] + bias[r], 0.f));
                *reinterpret_cast<u16x4*>(Kt + ((size_t)(b * ND + n)) * CQ + (mb - 32)) = h;
            } else {
#pragma unroll
                for (int r = 0; r < 4; ++r)
                    V[((size_t)(b * CD + (mb - 64 + r))) * ND + n] =
                        f2h(fmaxf(acc[ms][ns][r] + bias[r], 0.f));
            }
        }
    }
}

// ---------------- flash attention: 2 phase-skewed j-groups ----------------
// grid: NB*64 blocks (b, 64-row i-strip), 512 threads (8 waves, 2 groups of 4).
// Group g owns j-chunks k*128 + g*64 .. +64. Per chunk: roleA = QK^T (swapped)
// + softmax + P-write; roleB = PV. g0 runs A(k),B(k); g1 runs B(k-1),A(k) per
// barrier pair -> one group is always in MFMA-heavy roleB while the other is
// in VALU-heavy roleA.
__global__ __launch_bounds__(512, 2) void attn_kernel(
    const unsigned short* __restrict__ Qt, const unsigned short* __restrict__ Kt,
    const unsigned short* __restrict__ V, const float* __restrict__ x,
    const float* __restrict__ gamma, float* __restrict__ out)
{
    __shared__ __align__(16) unsigned char v_lds[2][2][256 * 128]; // [group][buf][c][128B]
    __shared__ __align__(16) unsigned char p_lds[2][64 * 128];     // [group][i][128B] f16
    __shared__ float scale_lds[2][64];
    __shared__ float mfin[2][64], lfin[2][64];
    __shared__ int   flags[2][2];

    const int tid  = threadIdx.x;
    const int lane = tid & 63;
    const int w8   = __builtin_amdgcn_readfirstlane(tid >> 6);
    const int g    = w8 >> 2;       // j-group
    const int ws   = w8 & 3;        // i-strip (roleA) / c-slice (roleB)
    const int m16  = lane & 15;
    const int g4   = lane >> 4;
    const int wg   = (blockIdx.x & 7) * 32 + (blockIdx.x >> 3);  // XCD swizzle
    const int b    = wg >> 6;
    const int i0   = (wg & 63) << 6;

    if (tid < 4) flags[tid >> 1][tid & 1] = 0;

    // Q as B-operand (col = i = m16, k = cq = g4*8+u) — same bytes as before
    const f16x8 qfrag = *reinterpret_cast<const f16x8*>(
        Qt + ((size_t)(b * ND + i0 + ws * 16 + m16)) * CQ + g4 * 8);

    // V staging: wave stages channels ws*64..+64 of its group's tile (pre-swizzled src)
    const int vgl = (lane & 7) ^ ((lane >> 3) & 7);
    const unsigned short* vpb =
        V + ((size_t)(b * CD + ws * 64 + (lane >> 3))) * ND + vgl * 8;
    // K as A-operand, straight from global: row j = jbase + t*16 + m16, 16B at cq=g4*8
    const unsigned short* kbase = Kt + ((size_t)(b * ND + m16)) * CQ + g4 * 8;

    f32x4 oacc[4][4];
#pragma unroll
    for (int a = 0; a < 4; ++a)
#pragma unroll
        for (int c = 0; c < 4; ++c) oacc[a][c] = (f32x4){0.f, 0.f, 0.f, 0.f};
    float mrow = -1e30f, lrow = 0.f;   // per-lane: softmax row i = ws*16 + m16
    const f32x4 zero4 = {0.f, 0.f, 0.f, 0.f};

    auto STAGEV = [&](int bb, int j) {
#pragma unroll
        for (int kk = 0; kk < 8; ++kk)
            gl_lds16(vpb + (size_t)kk * 8 * ND + j,
                     &v_lds[g][bb][(ws * 64 + kk * 8) * 128]);
    };
    auto LOADK = [&](f16x8 (&kr)[4], int j) {
#pragma unroll
        for (int t = 0; t < 4; ++t)
            kr[t] = *reinterpret_cast<const f16x8*>(kbase + (size_t)(j + t * 16) * CQ);
    };

    f16x8 kA[4], kB[4];
    { const int j0g = g * 64; STAGEV(0, j0g); LOADK(kA, j0g); }
    BARRIER();   // flags init + prologue ordering (no vmcnt drain)

    // roleA(k): issue next staging, QK^T(k) swapped, softmax, P write. 12 VMEM issues.
    auto ROLEA = [&](int k, f16x8 (&kc)[4], f16x8 (&kn)[4]) {
        const int jn = ((k + 1) * 128 + g * 64) & (ND - 1);   // wrap keeps loads in-bounds
        STAGEV((k + 1) & 1, jn);    // 8 gl_lds
        LOADK(kn, jn);              // 4 global loads
        f32x4 s[4];
#pragma unroll
        for (int t = 0; t < 4; ++t)   // swapped: D[j][i], col=i=m16, row j=t*16+g4*4+r
            s[t] = __builtin_amdgcn_mfma_f32_16x16x32_f16(kc[t], qfrag, zero4, 0, 0, 0);
        float pm = s[0][0];
#pragma unroll
        for (int t = 0; t < 4; ++t)
#pragma unroll
            for (int r = 0; r < 4; ++r) pm = fmaxf(pm, s[t][r]);
        pm = fmaxf(pm, __shfl_xor(pm, 16));
        pm = fmaxf(pm, __shfl_xor(pm, 32));
        float sc = 1.0f;
        const bool nearok = (pm <= mrow + 8.0f);   // defer-max, log2 domain
        if (__ballot(nearok) != ~0ull) {
            const float mnew = fmaxf(mrow, pm);
            sc = fexp2(mrow - mnew);
            mrow = mnew;
            if (lane == 0) flags[g][k & 1] = 1;
        }
        float rs = 0.f;
#pragma unroll
        for (int t = 0; t < 4; ++t)
#pragma unroll
            for (int r = 0; r < 4; ++r) { s[t][r] = fexp2(s[t][r] - mrow); rs += s[t][r]; }
        rs += __shfl_xor(rs, 16);
        rs += __shfl_xor(rs, 32);
        lrow = lrow * sc + rs;
        // P write: lane owns row i, j-quad t*16+g4*4 -> 4 x ds_write_b64, swizzled
        const int irow = ws * 16 + m16;
        const int iswz = (irow & 7) << 4;
#pragma unroll
        for (int t = 0; t < 4; ++t) {
            u32x2 pw;
            pw[0] = __builtin_bit_cast(unsigned int,
                        __builtin_amdgcn_cvt_pkrtz(s[t][0], s[t][1]));
            pw[1] = __builtin_bit_cast(unsigned int,
                        __builtin_amdgcn_cvt_pkrtz(s[t][2], s[t][3]));
            const int pa = (irow * 128 + t * 32 + g4 * 8) ^ iswz;
            *reinterpret_cast<u32x2*>(&p_lds[g][pa]) = pw;
        }
        if (g4 == 0) scale_lds[g][irow] = sc;
        // counted drain: 12 newest (this half's issues) may stay in flight;
        // guarantees chunk-k staging landed before the upcoming barrier.
        asm volatile("s_waitcnt vmcnt(12)" ::: "memory");
        __builtin_amdgcn_sched_barrier(0);
    };

    // roleB(k): PV for chunk k (reads own group's P + V tile)
    auto ROLEB = [&](int k) {
        const int vb = k & 1;
        const int do_resc = __builtin_amdgcn_readfirstlane(flags[g][k & 1]);
        if (lane == 0 && ws == 0) flags[g][(k & 1) ^ 1] = 0;  // safe window reset
        if (do_resc) {
#pragma unroll
            for (int is = 0; is < 4; ++is)
#pragma unroll
                for (int r = 0; r < 4; ++r) {
                    const float scv = scale_lds[g][is * 16 + g4 * 4 + r];
#pragma unroll
                    for (int cs = 0; cs < 4; ++cs) oacc[is][cs][r] *= scv;
                }
        }
        __builtin_amdgcn_s_setprio(1);
#pragma unroll
        for (int jh = 0; jh < 2; ++jh) {
            f16x8 vfr[4];
#pragma unroll
            for (int cs = 0; cs < 4; ++cs) {
                const int c  = ws * 64 + cs * 16 + m16;
                const int va = (c * 128 + jh * 64 + g4 * 16) ^ ((c & 7) << 4);
                vfr[cs] = *reinterpret_cast<const f16x8*>(&v_lds[g][vb][va]);
            }
#pragma unroll
            for (int is = 0; is < 4; ++is) {
                const int i  = is * 16 + m16;
                const int pa = (i * 128 + jh * 64 + g4 * 16) ^ ((i & 7) << 4);
                const f16x8 pf = *reinterpret_cast<const f16x8*>(&p_lds[g][pa]);
#pragma unroll
                for (int cs = 0; cs < 4; ++cs)
                    oacc[is][cs] = __builtin_amdgcn_mfma_f32_16x16x32_f16(
                        pf, vfr[cs], oacc[is][cs], 0, 0, 0);
            }
        }
        __builtin_amdgcn_s_setprio(0);
    };

#pragma unroll 1
    for (int k2 = 0; k2 < 16; ++k2) {
        const int k0 = 2 * k2, k1 = k0 + 1;
        if (g == 0) ROLEA(k0, kA, kB); else if (k0 > 0) ROLEB(k0 - 1);
        BARRIER();
        if (g == 0) ROLEB(k0); else ROLEA(k0, kA, kB);
        BARRIER();
        if (g == 0) ROLEA(k1, kB, kA); else ROLEB(k0);
        BARRIER();
        if (g == 0) ROLEB(k1); else ROLEA(k1, kB, kA);
        BARRIER();
    }
    if (g == 1) ROLEB(31);   // g1's pipeline tail

    // ---- merge the two j-groups (exact flash combine) ----
    if (g4 == 0) { mfin[g][ws * 16 + m16] = mrow; lfin[g][ws * 16 + m16] = lrow; }
    __syncthreads();

    float* ocomb = reinterpret_cast<float*>(&v_lds[0][0][0]);   // [64][257] f32
    if (g == 0) {
#pragma unroll
        for (int is = 0; is < 4; ++is)
#pragma unroll
            for (int r = 0; r < 4; ++r) {
                const int i = is * 16 + g4 * 4 + r;
                const float ms = fmaxf(mfin[0][i], mfin[1][i]);
                const float fa = fexp2(mfin[0][i] - ms);
#pragma unroll
                for (int cs = 0; cs < 4; ++cs)
                    ocomb[i * 257 + ws * 64 + cs * 16 + m16] = oacc[is][cs][r] * fa;
            }
    }
    __syncthreads();
    if (g == 1) {
        const float gm = gamma[0];
#pragma unroll
        for (int is = 0; is < 4; ++is)
#pragma unroll
            for (int r = 0; r < 4; ++r) {
                const int i  = is * 16 + g4 * 4 + r;
                const float ma = mfin[0][i], mb2 = mfin[1][i];
                const float ms = fmaxf(ma, mb2);
                const float fa = fexp2(ma - ms), fb = fexp2(mb2 - ms);
                const float den  = lfin[0][i] * fa + lfin[1][i] * fb;
                const float rinv = 1.0f / den;
#pragma unroll
                for (int cs = 0; cs < 4; ++cs) {
                    const int c = ws * 64 + cs * 16 + m16;
                    const float val = ocomb[i * 257 + c] + oacc[is][cs][r] * fb;
                    const size_t idx = ((size_t)(b * CD + c)) * ND + i0 + i;
                    out[idx] = gm * (val * rinv) + x[idx];
                }
            }
    }
}

extern "C" void kernel_launch(void* const* d_in, const int* in_sizes, int n_in,
                              void* d_out, int out_size, void* d_ws, size_t ws_size,
                              hipStream_t stream) {
    const float* x     = (const float*)d_in[0];
    const float* wq    = (const float*)d_in[1];
    const float* bq    = (const float*)d_in[2];
    const float* wk    = (const float*)d_in[3];
    const float* bk    = (const float*)d_in[4];
    const float* wv    = (const float*)d_in[5];
    const float* bv    = (const float*)d_in[6];
    const float* gamma = (const float*)d_in[7];

    unsigned short* Qt = (unsigned short*)d_ws;               // 1MB (scaled by log2e)
    unsigned short* Kt = Qt + (size_t)NB * ND * CQ;           // 1MB
    unsigned short* V  = Kt + (size_t)NB * ND * CQ;           // 8MB
    unsigned short* Wh = V + (size_t)NB * CD * ND;            // 160KB
    unsigned short* xh = Wh + (size_t)320 * CD;               // 8MB
    float* out = (float*)d_out;

    cvt_kernel<<<dim3(1104),   dim3(256), 0, stream>>>(x, wq, wk, wv, xh, Wh);
    proj_kernel<<<dim3(NB * 64), dim3(320), 0, stream>>>(Wh, xh, bq, bk, bv, Qt, Kt, V);
    attn_kernel<<<dim3(NB * 64), dim3(512), 0, stream>>>(Qt, Kt, V, x, gamma, out);
}